// Round 1
// baseline (356.218 us; speedup 1.0000x reference)
//
#include <hip/hip_runtime.h>
#include <stdint.h>

#define DEV __device__ __forceinline__

typedef uint32_t u32;
typedef uint16_t u16;
typedef __attribute__((ext_vector_type(4))) float f32x4;
typedef __attribute__((ext_vector_type(8))) __bf16 bf16x8;

DEV u16 f32_to_bf16(float f) {
  u32 u = __builtin_bit_cast(u32, f);
  u += 0x7FFFu + ((u >> 16) & 1u);
  return (u16)(u >> 16);
}
DEV float bf16_to_f32(u16 h) {
  u32 u = ((u32)h) << 16;
  return __builtin_bit_cast(float, u);
}
DEV bf16x8 load_frag16(const u16* p) {
  return __builtin_bit_cast(bf16x8, *(const uint4*)p);
}

// ---------------- convert fp32 -> bf16 (elementwise) ----------------
__global__ void cvt_f32_bf16(const float* __restrict__ in, u16* __restrict__ out, int n) {
  int i = (blockIdx.x * 256 + threadIdx.x) * 4;
  if (i >= n) return;
  float4 v = *(const float4*)(in + i);
  ushort4 o;
  o.x = f32_to_bf16(v.x); o.y = f32_to_bf16(v.y);
  o.z = f32_to_bf16(v.z); o.w = f32_to_bf16(v.w);
  *(ushort4*)(out + i) = o;
}

// ------------- transpose + convert: in[R][C] f32 -> out[C][R] bf16 -------------
__global__ void transpose_cvt(const float* __restrict__ in, u16* __restrict__ out, int R, int C) {
  __shared__ float tile[32][33];
  int bx = blockIdx.x * 32;  // col base (C)
  int by = blockIdx.y * 32;  // row base (R)
  int tx = threadIdx.x & 31;
  int ty = threadIdx.x >> 5;  // 0..7
#pragma unroll
  for (int i = 0; i < 32; i += 8)
    tile[ty + i][tx] = in[(size_t)(by + ty + i) * C + bx + tx];
  __syncthreads();
#pragma unroll
  for (int i = 0; i < 32; i += 8)
    out[(size_t)(bx + ty + i) * R + by + tx] = f32_to_bf16(tile[tx][ty + i]);
}

// ---------------- bf16 GEMM: C[M][N] = A[M][K] * Bt[N][K]^T + bias ----------------
// BM=BN=128, BK=64. 256 threads = 4 waves in 2x2, each wave 64x64 (4x4 16x16 frags).
// LDS row stride 72 elems (144B) -> fragment ds_read_b128 spread across bank groups.
template <int OUT_BF16>
__global__ __launch_bounds__(256, 2) void gemm_bf16(
    const u16* __restrict__ A, const u16* __restrict__ Bt,
    const float* __restrict__ bias, void* __restrict__ Cout,
    int M, int N, int K) {
  const int LDT = 72;
  __shared__ __attribute__((aligned(16))) u16 As[128 * 72];
  __shared__ __attribute__((aligned(16))) u16 Bs[128 * 72];
  int tid = threadIdx.x;
  int m0 = blockIdx.y * 128;
  int n0 = blockIdx.x * 128;
  int w = tid >> 6, l = tid & 63;
  int wr = w >> 1, wc = w & 1;
  int lr = l & 15, lg = l >> 4;

  f32x4 acc[4][4];
#pragma unroll
  for (int i = 0; i < 4; i++)
#pragma unroll
    for (int j = 0; j < 4; j++) acc[i][j] = (f32x4)0.0f;

  for (int kt = 0; kt < K; kt += 64) {
    __syncthreads();
#pragma unroll
    for (int p = 0; p < 4; ++p) {
      int chunk = p * 256 + tid;        // 1024 chunks of 16B per tile
      int row = chunk >> 3, cc = chunk & 7;
      *(uint4*)(As + row * LDT + cc * 8) =
          *(const uint4*)(A + (size_t)(m0 + row) * K + kt + cc * 8);
      *(uint4*)(Bs + row * LDT + cc * 8) =
          *(const uint4*)(Bt + (size_t)(n0 + row) * K + kt + cc * 8);
    }
    __syncthreads();
#pragma unroll
    for (int kk = 0; kk < 2; ++kk) {
      bf16x8 af[4], bfr[4];
#pragma unroll
      for (int i = 0; i < 4; i++)
        af[i] = load_frag16(As + (wr * 64 + i * 16 + lr) * LDT + kk * 32 + lg * 8);
#pragma unroll
      for (int j = 0; j < 4; j++)
        bfr[j] = load_frag16(Bs + (wc * 64 + j * 16 + lr) * LDT + kk * 32 + lg * 8);
#pragma unroll
      for (int i = 0; i < 4; i++)
#pragma unroll
        for (int j = 0; j < 4; j++)
          acc[i][j] = __builtin_amdgcn_mfma_f32_16x16x32_bf16(af[i], bfr[j], acc[i][j], 0, 0, 0);
    }
  }
#pragma unroll
  for (int i = 0; i < 4; i++) {
#pragma unroll
    for (int j = 0; j < 4; j++) {
      int col = n0 + wc * 64 + j * 16 + lr;
      float bv = bias[col];
#pragma unroll
      for (int r = 0; r < 4; r++) {
        int row = m0 + wr * 64 + i * 16 + lg * 4 + r;
        float v = acc[i][j][r] + bv;
        if (OUT_BF16)
          ((u16*)Cout)[(size_t)row * N + col] = f32_to_bf16(v);
        else
          ((float*)Cout)[(size_t)row * N + col] = v;
      }
    }
  }
}

// ---------------- causal flash attention ----------------
// qkvb: [B*L][3072] bf16 (Q|K|V). attnb: [B*L][1024] bf16 (already head-merged).
// grid: (L/128, B*H). 4 waves x 32 q-rows. KV tiles of 64.
__global__ __launch_bounds__(256, 2) void attn_kernel(
    const u16* __restrict__ qkvb, u16* __restrict__ attnb) {
  const int LDT = 72;
  __shared__ __attribute__((aligned(16))) u16 Ks[64 * 72];
  __shared__ __attribute__((aligned(16))) u16 Vt[64 * 72];
  __shared__ __attribute__((aligned(16))) u16 Pl[4][32 * 72];
  int tid = threadIdx.x;
  int w = tid >> 6, l = tid & 63;
  int lr = l & 15, lg = l >> 4;
  int bh = blockIdx.y;
  int b = bh >> 4, h = bh & 15;
  int q0 = blockIdx.x * 128;
  const u16* base = qkvb + (size_t)b * 2048 * 3072;

  // Q fragments (scaled by 1/sqrt(64)=0.125, exact in bf16)
  bf16x8 qf[2][2];
#pragma unroll
  for (int i = 0; i < 2; i++)
#pragma unroll
    for (int kk = 0; kk < 2; kk++) {
      int row = q0 + w * 32 + i * 16 + lr;
      uint4 v = *(const uint4*)(base + (size_t)row * 3072 + h * 64 + kk * 32 + lg * 8);
      u32 wd[4] = {v.x, v.y, v.z, v.w};
#pragma unroll
      for (int e = 0; e < 4; e++) {
        u16 lo = (u16)(wd[e] & 0xFFFFu), hi = (u16)(wd[e] >> 16);
        lo = (u16)(__builtin_bit_cast(u32, bf16_to_f32(lo) * 0.125f) >> 16);
        hi = (u16)(__builtin_bit_cast(u32, bf16_to_f32(hi) * 0.125f) >> 16);
        wd[e] = (u32)lo | ((u32)hi << 16);
      }
      uint4 sv; sv.x = wd[0]; sv.y = wd[1]; sv.z = wd[2]; sv.w = wd[3];
      qf[i][kk] = __builtin_bit_cast(bf16x8, sv);
    }

  float m_[8], lsum[8];
  f32x4 of[2][4];
#pragma unroll
  for (int i = 0; i < 8; i++) { m_[i] = -1e30f; lsum[i] = 0.f; }
#pragma unroll
  for (int i = 0; i < 2; i++)
#pragma unroll
    for (int j = 0; j < 4; j++) of[i][j] = (f32x4)0.0f;

  int nkv = (q0 + 128) >> 6;
  for (int kvt = 0; kvt < nkv; ++kvt) {
    int kv0 = kvt << 6;
    __syncthreads();
    // stage K (row-major) and V (transposed)
#pragma unroll
    for (int p = 0; p < 2; ++p) {
      int chunk = p * 256 + tid;     // 512 chunks of 16B
      int row = chunk >> 3, cc = chunk & 7;
      const u16* kp = base + (size_t)(kv0 + row) * 3072 + 1024 + h * 64 + cc * 8;
      *(uint4*)(Ks + row * LDT + cc * 8) = *(const uint4*)kp;
      const u16* vp = base + (size_t)(kv0 + row) * 3072 + 2048 + h * 64 + cc * 8;
      uint4 vv = *(const uint4*)vp;
      u32 wd[4] = {vv.x, vv.y, vv.z, vv.w};
#pragma unroll
      for (int e = 0; e < 4; e++) {
        Vt[(cc * 8 + 2 * e) * LDT + row] = (u16)(wd[e] & 0xFFFFu);
        Vt[(cc * 8 + 2 * e + 1) * LDT + row] = (u16)(wd[e] >> 16);
      }
    }
    __syncthreads();

    if (kv0 <= q0 + w * 32 + 31) {   // wave-uniform: skip fully-masked tiles
      f32x4 S[2][4];
#pragma unroll
      for (int i = 0; i < 2; i++)
#pragma unroll
        for (int j = 0; j < 4; j++) S[i][j] = (f32x4)0.0f;
#pragma unroll
      for (int kk = 0; kk < 2; ++kk) {
        bf16x8 kb[4];
#pragma unroll
        for (int j = 0; j < 4; j++)
          kb[j] = load_frag16(Ks + (j * 16 + lr) * LDT + kk * 32 + lg * 8);
#pragma unroll
        for (int i = 0; i < 2; i++)
#pragma unroll
          for (int j = 0; j < 4; j++)
            S[i][j] = __builtin_amdgcn_mfma_f32_16x16x32_bf16(qf[i][kk], kb[j], S[i][j], 0, 0, 0);
      }
      if (kv0 + 63 > q0 + w * 32) {  // partially-masked tile for this wave
#pragma unroll
        for (int i = 0; i < 2; i++)
#pragma unroll
          for (int j = 0; j < 4; j++)
#pragma unroll
            for (int r = 0; r < 4; r++) {
              int rowg = q0 + w * 32 + i * 16 + lg * 4 + r;
              int colg = kv0 + j * 16 + lr;
              if (colg > rowg) S[i][j][r] = -1e30f;
            }
      }
      // online softmax (rows live on 16-lane col groups)
#pragma unroll
      for (int i = 0; i < 2; i++) {
#pragma unroll
        for (int r = 0; r < 4; r++) {
          int idx = i * 4 + r;
          float tm = fmaxf(fmaxf(S[i][0][r], S[i][1][r]), fmaxf(S[i][2][r], S[i][3][r]));
#pragma unroll
          for (int off = 1; off < 16; off <<= 1) tm = fmaxf(tm, __shfl_xor(tm, off));
          float mn = fmaxf(m_[idx], tm);
          float f = __expf(m_[idx] - mn);
          m_[idx] = mn;
          float rs = 0.f;
#pragma unroll
          for (int j = 0; j < 4; j++) {
            float pv = __expf(S[i][j][r] - mn);
            S[i][j][r] = pv;
            rs += pv;
          }
#pragma unroll
          for (int off = 1; off < 16; off <<= 1) rs += __shfl_xor(rs, off);
          lsum[idx] = lsum[idx] * f + rs;
#pragma unroll
          for (int jd = 0; jd < 4; jd++) of[i][jd][r] *= f;
        }
      }
      // P -> LDS (wave-private; LDS ops in-order within a wave)
#pragma unroll
      for (int i = 0; i < 2; i++)
#pragma unroll
        for (int j = 0; j < 4; j++)
#pragma unroll
          for (int r = 0; r < 4; r++)
            Pl[w][(i * 16 + lg * 4 + r) * LDT + j * 16 + lr] = f32_to_bf16(S[i][j][r]);
      // PV
#pragma unroll
      for (int ks = 0; ks < 2; ++ks) {
        bf16x8 ap[2], vb[4];
#pragma unroll
        for (int i = 0; i < 2; i++)
          ap[i] = load_frag16(Pl[w] + (i * 16 + lr) * LDT + ks * 32 + lg * 8);
#pragma unroll
        for (int jd = 0; jd < 4; jd++)
          vb[jd] = load_frag16(Vt + (jd * 16 + lr) * LDT + ks * 32 + lg * 8);
#pragma unroll
        for (int i = 0; i < 2; i++)
#pragma unroll
          for (int jd = 0; jd < 4; jd++)
            of[i][jd] = __builtin_amdgcn_mfma_f32_16x16x32_bf16(ap[i], vb[jd], of[i][jd], 0, 0, 0);
      }
    }
  }
  // epilogue: O /= lsum, store bf16 head-merged
#pragma unroll
  for (int i = 0; i < 2; i++)
#pragma unroll
    for (int jd = 0; jd < 4; jd++)
#pragma unroll
      for (int r = 0; r < 4; r++) {
        int idx = i * 4 + r;
        int row = q0 + w * 32 + i * 16 + lg * 4 + r;
        int col = h * 64 + jd * 16 + lr;
        float v = of[i][jd][r] / lsum[idx];
        attnb[((size_t)b * 2048 + row) * 1024 + col] = f32_to_bf16(v);
      }
}

extern "C" void kernel_launch(void* const* d_in, const int* in_sizes, int n_in,
                              void* d_out, int out_size, void* d_ws, size_t ws_size,
                              hipStream_t stream) {
  const float* x = (const float*)d_in[0];
  const float* Wqkv = (const float*)d_in[1];
  const float* bqkv = (const float*)d_in[2];
  const float* Wproj = (const float*)d_in[3];
  const float* bproj = (const float*)d_in[4];
  float* out = (float*)d_out;

  char* ws = (char*)d_ws;
  u16* xb    = (u16*)(ws);                 // 8192*1024*2  = 16,777,216
  u16* wqT   = (u16*)(ws + 16777216);      // 3072*1024*2  =  6,291,456
  u16* wpT   = (u16*)(ws + 23068672);      // 1024*1024*2  =  2,097,152
  u16* qkvb  = (u16*)(ws + 25165824);      // 8192*3072*2  = 50,331,648
  u16* attnb = (u16*)(ws + 75497472);      // 8192*1024*2  = 16,777,216  (total ~92MB)

  cvt_f32_bf16<<<8192, 256, 0, stream>>>(x, xb, 8388608);
  transpose_cvt<<<dim3(96, 32), 256, 0, stream>>>(Wqkv, wqT, 1024, 3072);
  transpose_cvt<<<dim3(32, 32), 256, 0, stream>>>(Wproj, wpT, 1024, 1024);
  gemm_bf16<1><<<dim3(24, 64), 256, 0, stream>>>(xb, wqT, bqkv, (void*)qkvb, 8192, 3072, 1024);
  attn_kernel<<<dim3(16, 64), 256, 0, stream>>>(qkvb, attnb);
  gemm_bf16<0><<<dim3(8, 64), 256, 0, stream>>>(attnb, wpT, bproj, (void*)out, 8192, 1024, 1024);
}

// Round 2
// 241.838 us; speedup vs baseline: 1.4730x; 1.4730x over previous
//
#include <hip/hip_runtime.h>
#include <stdint.h>

#define DEV __device__ __forceinline__

typedef uint32_t u32;
typedef uint16_t u16;
typedef __attribute__((ext_vector_type(4))) float f32x4;
typedef __attribute__((ext_vector_type(8))) __bf16 bf16x8;

DEV u16 f32_to_bf16(float f) {
  u32 u = __builtin_bit_cast(u32, f);
  u += 0x7FFFu + ((u >> 16) & 1u);
  return (u16)(u >> 16);
}
DEV float bf16_to_f32(u16 h) {
  u32 u = ((u32)h) << 16;
  return __builtin_bit_cast(float, u);
}
DEV bf16x8 load_frag16(const u16* p) {
  return __builtin_bit_cast(bf16x8, *(const uint4*)p);
}

// ---------------- convert fp32 -> bf16 (elementwise) ----------------
__global__ void cvt_f32_bf16(const float* __restrict__ in, u16* __restrict__ out, int n) {
  int i = (blockIdx.x * 256 + threadIdx.x) * 4;
  if (i >= n) return;
  float4 v = *(const float4*)(in + i);
  ushort4 o;
  o.x = f32_to_bf16(v.x); o.y = f32_to_bf16(v.y);
  o.z = f32_to_bf16(v.z); o.w = f32_to_bf16(v.w);
  *(ushort4*)(out + i) = o;
}

// ------------- transpose + convert: in[R][C] f32 -> out[C][R] bf16 -------------
__global__ void transpose_cvt(const float* __restrict__ in, u16* __restrict__ out, int R, int C) {
  __shared__ float tile[32][33];
  int bx = blockIdx.x * 32;  // col base (C)
  int by = blockIdx.y * 32;  // row base (R)
  int tx = threadIdx.x & 31;
  int ty = threadIdx.x >> 5;  // 0..7
#pragma unroll
  for (int i = 0; i < 32; i += 8)
    tile[ty + i][tx] = in[(size_t)(by + ty + i) * C + bx + tx];
  __syncthreads();
#pragma unroll
  for (int i = 0; i < 32; i += 8)
    out[(size_t)(bx + ty + i) * R + by + tx] = f32_to_bf16(tile[tx][ty + i]);
}

// ------------- transpose V: qkvb[b*2048+l][3072] (V slice) -> vTg[bh][64][2048] -------------
__global__ void transpose_v(const u16* __restrict__ qkvb, u16* __restrict__ vTg) {
  const int LDT = 72;
  __shared__ __attribute__((aligned(16))) u16 t[64 * 72];
  int bh = blockIdx.y;  // 0..63
  int b = bh >> 4, h = bh & 15;
  int l0 = blockIdx.x * 64;
  int tid = threadIdx.x;
#pragma unroll
  for (int p = 0; p < 2; ++p) {
    int chunk = p * 256 + tid;
    int row = chunk >> 3, cc = chunk & 7;
    *(uint4*)(t + row * LDT + cc * 8) =
        *(const uint4*)(qkvb + (size_t)(b * 2048 + l0 + row) * 3072 + 2048 + h * 64 + cc * 8);
  }
  __syncthreads();
#pragma unroll
  for (int p = 0; p < 2; ++p) {
    int chunk = p * 256 + tid;
    int d = chunk >> 3, cc = chunk & 7;
    ushort4 o0, o1;
    o0.x = t[(cc * 8 + 0) * LDT + d]; o0.y = t[(cc * 8 + 1) * LDT + d];
    o0.z = t[(cc * 8 + 2) * LDT + d]; o0.w = t[(cc * 8 + 3) * LDT + d];
    o1.x = t[(cc * 8 + 4) * LDT + d]; o1.y = t[(cc * 8 + 5) * LDT + d];
    o1.z = t[(cc * 8 + 6) * LDT + d]; o1.w = t[(cc * 8 + 7) * LDT + d];
    u16* op = vTg + ((size_t)bh * 64 + d) * 2048 + l0;
    // note: within a d-row the 8 kv values live in LDS rows cc*8..cc*8+7; we
    // write them as two 8B chunks so the global store is coalesced per d-row.
    *(ushort4*)(op + cc * 8 + 0) = o0;
    *(ushort4*)(op + cc * 8 + 4) = o1;
  }
}

// ---------------- bf16 GEMM: C[M][N] = A[M][K] * Bt[N][K]^T + bias ----------------
template <int OUT_BF16>
__global__ __launch_bounds__(256, 2) void gemm_bf16(
    const u16* __restrict__ A, const u16* __restrict__ Bt,
    const float* __restrict__ bias, void* __restrict__ Cout,
    int M, int N, int K) {
  const int LDT = 72;
  __shared__ __attribute__((aligned(16))) u16 As[128 * 72];
  __shared__ __attribute__((aligned(16))) u16 Bs[128 * 72];
  int tid = threadIdx.x;
  int m0 = blockIdx.y * 128;
  int n0 = blockIdx.x * 128;
  int w = tid >> 6, l = tid & 63;
  int wr = w >> 1, wc = w & 1;
  int lr = l & 15, lg = l >> 4;

  f32x4 acc[4][4];
#pragma unroll
  for (int i = 0; i < 4; i++)
#pragma unroll
    for (int j = 0; j < 4; j++) acc[i][j] = (f32x4)0.0f;

  for (int kt = 0; kt < K; kt += 64) {
    __syncthreads();
#pragma unroll
    for (int p = 0; p < 4; ++p) {
      int chunk = p * 256 + tid;        // 1024 chunks of 16B per tile
      int row = chunk >> 3, cc = chunk & 7;
      *(uint4*)(As + row * LDT + cc * 8) =
          *(const uint4*)(A + (size_t)(m0 + row) * K + kt + cc * 8);
      *(uint4*)(Bs + row * LDT + cc * 8) =
          *(const uint4*)(Bt + (size_t)(n0 + row) * K + kt + cc * 8);
    }
    __syncthreads();
#pragma unroll
    for (int kk = 0; kk < 2; ++kk) {
      bf16x8 af[4], bfr[4];
#pragma unroll
      for (int i = 0; i < 4; i++)
        af[i] = load_frag16(As + (wr * 64 + i * 16 + lr) * LDT + kk * 32 + lg * 8);
#pragma unroll
      for (int j = 0; j < 4; j++)
        bfr[j] = load_frag16(Bs + (wc * 64 + j * 16 + lr) * LDT + kk * 32 + lg * 8);
#pragma unroll
      for (int i = 0; i < 4; i++)
#pragma unroll
        for (int j = 0; j < 4; j++)
          acc[i][j] = __builtin_amdgcn_mfma_f32_16x16x32_bf16(af[i], bfr[j], acc[i][j], 0, 0, 0);
    }
  }
#pragma unroll
  for (int i = 0; i < 4; i++) {
#pragma unroll
    for (int j = 0; j < 4; j++) {
      int col = n0 + wc * 64 + j * 16 + lr;
      float bv = bias[col];
#pragma unroll
      for (int r = 0; r < 4; r++) {
        int row = m0 + wr * 64 + i * 16 + lg * 4 + r;
        float v = acc[i][j][r] + bv;
        if (OUT_BF16)
          ((u16*)Cout)[(size_t)row * N + col] = f32_to_bf16(v);
        else
          ((float*)Cout)[(size_t)row * N + col] = v;
      }
    }
  }
}

// ---------------- causal flash attention ----------------
// qkvb: [B*L][3072] bf16 (Q|K|V). vTg: [bh][64][2048] bf16. attnb: [B*L][1024] bf16.
// grid: (8, B*H). Each block does q-tile x then 15-x -> uniform 34 KV-iters.
__global__ __launch_bounds__(256, 2) void attn_kernel(
    const u16* __restrict__ qkvb, const u16* __restrict__ vTg,
    u16* __restrict__ attnb) {
  const int LDT = 72;
  __shared__ __attribute__((aligned(16))) u16 Ks[64 * 72];
  __shared__ __attribute__((aligned(16))) u16 Vt[64 * 72];
  __shared__ __attribute__((aligned(16))) u16 Pl[4][32 * 72];
  int tid = threadIdx.x;
  int w = tid >> 6, l = tid & 63;
  int lr = l & 15, lg = l >> 4;
  int bh = blockIdx.y;
  int b = bh >> 4, h = bh & 15;
  const u16* base = qkvb + (size_t)b * 2048 * 3072;
  const u16* vbase = vTg + (size_t)bh * 64 * 2048;

  for (int half = 0; half < 2; ++half) {
    int qt = half ? (15 - (int)blockIdx.x) : (int)blockIdx.x;
    int q0 = qt * 128;

    // Q fragments (scaled by 1/sqrt(64)=0.125, exact in bf16)
    bf16x8 qf[2][2];
#pragma unroll
    for (int i = 0; i < 2; i++)
#pragma unroll
      for (int kk = 0; kk < 2; kk++) {
        int row = q0 + w * 32 + i * 16 + lr;
        uint4 v = *(const uint4*)(base + (size_t)row * 3072 + h * 64 + kk * 32 + lg * 8);
        u32 wd[4] = {v.x, v.y, v.z, v.w};
#pragma unroll
        for (int e = 0; e < 4; e++) {
          u16 lo = (u16)(wd[e] & 0xFFFFu), hi = (u16)(wd[e] >> 16);
          lo = (u16)(__builtin_bit_cast(u32, bf16_to_f32(lo) * 0.125f) >> 16);
          hi = (u16)(__builtin_bit_cast(u32, bf16_to_f32(hi) * 0.125f) >> 16);
          wd[e] = (u32)lo | ((u32)hi << 16);
        }
        uint4 sv; sv.x = wd[0]; sv.y = wd[1]; sv.z = wd[2]; sv.w = wd[3];
        qf[i][kk] = __builtin_bit_cast(bf16x8, sv);
      }

    float m_[8], lsum[8];
    f32x4 of[2][4];
#pragma unroll
    for (int i = 0; i < 8; i++) { m_[i] = -1e30f; lsum[i] = 0.f; }
#pragma unroll
    for (int i = 0; i < 2; i++)
#pragma unroll
      for (int j = 0; j < 4; j++) of[i][j] = (f32x4)0.0f;

    int nkv = (q0 + 128) >> 6;
    for (int kvt = 0; kvt < nkv; ++kvt) {
      int kv0 = kvt << 6;
      __syncthreads();
      // stage K (row-major) and V (pre-transposed) — both b128, conflict-free
#pragma unroll
      for (int p = 0; p < 2; ++p) {
        int chunk = p * 256 + tid;     // 512 chunks of 16B each
        int row = chunk >> 3, cc = chunk & 7;
        *(uint4*)(Ks + row * LDT + cc * 8) =
            *(const uint4*)(base + (size_t)(kv0 + row) * 3072 + 1024 + h * 64 + cc * 8);
        *(uint4*)(Vt + row * LDT + cc * 8) =
            *(const uint4*)(vbase + (size_t)row * 2048 + kv0 + cc * 8);
      }
      __syncthreads();

      if (kv0 <= q0 + w * 32 + 31) {   // wave-uniform: skip fully-masked tiles
        f32x4 S[2][4];
#pragma unroll
        for (int i = 0; i < 2; i++)
#pragma unroll
          for (int j = 0; j < 4; j++) S[i][j] = (f32x4)0.0f;
#pragma unroll
        for (int kk = 0; kk < 2; ++kk) {
          bf16x8 kb[4];
#pragma unroll
          for (int j = 0; j < 4; j++)
            kb[j] = load_frag16(Ks + (j * 16 + lr) * LDT + kk * 32 + lg * 8);
#pragma unroll
          for (int i = 0; i < 2; i++)
#pragma unroll
            for (int j = 0; j < 4; j++)
              S[i][j] = __builtin_amdgcn_mfma_f32_16x16x32_bf16(qf[i][kk], kb[j], S[i][j], 0, 0, 0);
        }
        if (kv0 + 63 > q0 + w * 32) {  // partially-masked tile for this wave
#pragma unroll
          for (int i = 0; i < 2; i++)
#pragma unroll
            for (int j = 0; j < 4; j++)
#pragma unroll
              for (int r = 0; r < 4; r++) {
                int rowg = q0 + w * 32 + i * 16 + lg * 4 + r;
                int colg = kv0 + j * 16 + lr;
                if (colg > rowg) S[i][j][r] = -1e30f;
              }
        }
        // online softmax (rows live on 16-lane col groups)
#pragma unroll
        for (int i = 0; i < 2; i++) {
#pragma unroll
          for (int r = 0; r < 4; r++) {
            int idx = i * 4 + r;
            float tm = fmaxf(fmaxf(S[i][0][r], S[i][1][r]), fmaxf(S[i][2][r], S[i][3][r]));
#pragma unroll
            for (int off = 1; off < 16; off <<= 1) tm = fmaxf(tm, __shfl_xor(tm, off));
            float mn = fmaxf(m_[idx], tm);
            float f = __expf(m_[idx] - mn);
            m_[idx] = mn;
            float rs = 0.f;
#pragma unroll
            for (int j = 0; j < 4; j++) {
              float pv = __expf(S[i][j][r] - mn);
              S[i][j][r] = pv;
              rs += pv;
            }
#pragma unroll
            for (int off = 1; off < 16; off <<= 1) rs += __shfl_xor(rs, off);
            lsum[idx] = lsum[idx] * f + rs;
#pragma unroll
            for (int jd = 0; jd < 4; jd++) of[i][jd][r] *= f;
          }
        }
        // P -> LDS (wave-private; LDS ops in-order within a wave)
#pragma unroll
        for (int i = 0; i < 2; i++)
#pragma unroll
          for (int j = 0; j < 4; j++)
#pragma unroll
            for (int r = 0; r < 4; r++)
              Pl[w][(i * 16 + lg * 4 + r) * LDT + j * 16 + lr] = f32_to_bf16(S[i][j][r]);
        // PV
#pragma unroll
        for (int ks = 0; ks < 2; ++ks) {
          bf16x8 ap[2], vb[4];
#pragma unroll
          for (int i = 0; i < 2; i++)
            ap[i] = load_frag16(Pl[w] + (i * 16 + lr) * LDT + ks * 32 + lg * 8);
#pragma unroll
          for (int jd = 0; jd < 4; jd++)
            vb[jd] = load_frag16(Vt + (jd * 16 + lr) * LDT + ks * 32 + lg * 8);
#pragma unroll
          for (int i = 0; i < 2; i++)
#pragma unroll
            for (int jd = 0; jd < 4; jd++)
              of[i][jd] = __builtin_amdgcn_mfma_f32_16x16x32_bf16(ap[i], vb[jd], of[i][jd], 0, 0, 0);
        }
      }
    }
    // epilogue: O /= lsum, store bf16 head-merged
#pragma unroll
    for (int i = 0; i < 2; i++)
#pragma unroll
      for (int jd = 0; jd < 4; jd++)
#pragma unroll
        for (int r = 0; r < 4; r++) {
          int idx = i * 4 + r;
          int row = q0 + w * 32 + i * 16 + lg * 4 + r;
          int col = h * 64 + jd * 16 + lr;
          float v = of[i][jd][r] / lsum[idx];
          attnb[((size_t)b * 2048 + row) * 1024 + col] = f32_to_bf16(v);
        }
  }
}

extern "C" void kernel_launch(void* const* d_in, const int* in_sizes, int n_in,
                              void* d_out, int out_size, void* d_ws, size_t ws_size,
                              hipStream_t stream) {
  const float* x = (const float*)d_in[0];
  const float* Wqkv = (const float*)d_in[1];
  const float* bqkv = (const float*)d_in[2];
  const float* Wproj = (const float*)d_in[3];
  const float* bproj = (const float*)d_in[4];
  float* out = (float*)d_out;

  char* ws = (char*)d_ws;
  u16* xb    = (u16*)(ws);                 // 8192*1024*2  = 16,777,216 (dead after gemm1)
  u16* vTg   = (u16*)(ws);                 // 64*64*2048*2 = 16,777,216 (reuses xb region)
  u16* wqT   = (u16*)(ws + 16777216);      // 3072*1024*2  =  6,291,456
  u16* wpT   = (u16*)(ws + 23068672);      // 1024*1024*2  =  2,097,152
  u16* qkvb  = (u16*)(ws + 25165824);      // 8192*3072*2  = 50,331,648
  u16* attnb = (u16*)(ws + 75497472);      // 8192*1024*2  = 16,777,216  (total ~92MB)

  cvt_f32_bf16<<<8192, 256, 0, stream>>>(x, xb, 8388608);
  transpose_cvt<<<dim3(96, 32), 256, 0, stream>>>(Wqkv, wqT, 1024, 3072);
  transpose_cvt<<<dim3(32, 32), 256, 0, stream>>>(Wproj, wpT, 1024, 1024);
  gemm_bf16<1><<<dim3(24, 64), 256, 0, stream>>>(xb, wqT, bqkv, (void*)qkvb, 8192, 3072, 1024);
  transpose_v<<<dim3(32, 64), 256, 0, stream>>>(qkvb, vTg);
  attn_kernel<<<dim3(8, 64), 256, 0, stream>>>(qkvb, vTg, attnb);
  gemm_bf16<0><<<dim3(8, 64), 256, 0, stream>>>(attnb, wpT, bproj, (void*)out, 8192, 1024, 1024);
}

// Round 3
// 196.393 us; speedup vs baseline: 1.8138x; 1.2314x over previous
//
#include <hip/hip_runtime.h>
#include <stdint.h>

#define DEV __device__ __forceinline__

typedef uint32_t u32;
typedef uint16_t u16;
typedef __attribute__((ext_vector_type(4))) float f32x4;
typedef __attribute__((ext_vector_type(8))) __bf16 bf16x8;

DEV u16 f32_to_bf16(float f) {
  u32 u = __builtin_bit_cast(u32, f);
  u += 0x7FFFu + ((u >> 16) & 1u);
  return (u16)(u >> 16);
}
DEV float bf16_to_f32(u16 h) {
  u32 u = ((u32)h) << 16;
  return __builtin_bit_cast(float, u);
}
DEV bf16x8 load_frag16(const u16* p) {
  return __builtin_bit_cast(bf16x8, *(const uint4*)p);
}

// global -> LDS direct (16B per lane, dest = wave-uniform base + lane*16)
DEV void gl_lds16(const u16* g, u16* l) {
  __builtin_amdgcn_global_load_lds(
      (__attribute__((address_space(1))) void*)(u16*)g,
      (__attribute__((address_space(3))) void*)l, 16, 0, 0);
}

// XOR-swizzled address into a [rows][64 bf16] tile (128 B rows).
// Content was staged with source chunk cc ^ (row&7), so logical colByte is
// recovered by the same XOR on bytes 4..6.
DEV const u16* swz(const u16* basep, int row, int colByte) {
  return (const u16*)((const char*)basep + row * 128 + (colByte ^ ((row & 7) << 4)));
}
DEV u16* swzw(u16* basep, int row, int colByte) {
  return (u16*)((char*)basep + row * 128 + (colByte ^ ((row & 7) << 4)));
}

// ---------------- convert fp32 -> bf16 (elementwise) ----------------
__global__ void cvt_f32_bf16(const float* __restrict__ in, u16* __restrict__ out, int n) {
  int i = (blockIdx.x * 256 + threadIdx.x) * 4;
  if (i >= n) return;
  float4 v = *(const float4*)(in + i);
  ushort4 o;
  o.x = f32_to_bf16(v.x); o.y = f32_to_bf16(v.y);
  o.z = f32_to_bf16(v.z); o.w = f32_to_bf16(v.w);
  *(ushort4*)(out + i) = o;
}

// ------------- transpose + convert: in[R][C] f32 -> out[C][R] bf16 -------------
__global__ void transpose_cvt(const float* __restrict__ in, u16* __restrict__ out, int R, int C) {
  __shared__ float tile[32][33];
  int bx = blockIdx.x * 32;
  int by = blockIdx.y * 32;
  int tx = threadIdx.x & 31;
  int ty = threadIdx.x >> 5;
#pragma unroll
  for (int i = 0; i < 32; i += 8)
    tile[ty + i][tx] = in[(size_t)(by + ty + i) * C + bx + tx];
  __syncthreads();
#pragma unroll
  for (int i = 0; i < 32; i += 8)
    out[(size_t)(bx + ty + i) * R + by + tx] = f32_to_bf16(tile[tx][ty + i]);
}

// ------------- transpose V: qkvb[b*2048+l][3072] (V slice) -> vTg[bh][64][2048] -------------
__global__ void transpose_v(const u16* __restrict__ qkvb, u16* __restrict__ vTg) {
  const int LDT = 72;
  __shared__ __attribute__((aligned(16))) u16 t[64 * 72];
  int bh = blockIdx.y;
  int b = bh >> 4, h = bh & 15;
  int l0 = blockIdx.x * 64;
  int tid = threadIdx.x;
#pragma unroll
  for (int p = 0; p < 2; ++p) {
    int chunk = p * 256 + tid;
    int row = chunk >> 3, cc = chunk & 7;
    *(uint4*)(t + row * LDT + cc * 8) =
        *(const uint4*)(qkvb + (size_t)(b * 2048 + l0 + row) * 3072 + 2048 + h * 64 + cc * 8);
  }
  __syncthreads();
#pragma unroll
  for (int p = 0; p < 2; ++p) {
    int chunk = p * 256 + tid;
    int d = chunk >> 3, cc = chunk & 7;
    ushort4 o0, o1;
    o0.x = t[(cc * 8 + 0) * LDT + d]; o0.y = t[(cc * 8 + 1) * LDT + d];
    o0.z = t[(cc * 8 + 2) * LDT + d]; o0.w = t[(cc * 8 + 3) * LDT + d];
    o1.x = t[(cc * 8 + 4) * LDT + d]; o1.y = t[(cc * 8 + 5) * LDT + d];
    o1.z = t[(cc * 8 + 6) * LDT + d]; o1.w = t[(cc * 8 + 7) * LDT + d];
    u16* op = vTg + ((size_t)bh * 64 + d) * 2048 + l0;
    *(ushort4*)(op + cc * 8 + 0) = o0;
    *(ushort4*)(op + cc * 8 + 4) = o1;
  }
}

// ---------------- bf16 GEMM: C[M][N] = A[M][K] * Bt[N][K]^T + bias ----------------
// 128x128x64 tiles, 4 waves 2x2, global_load_lds staging + XOR-swizzled LDS.
template <int OUT_BF16>
__global__ __launch_bounds__(256, 2) void gemm_bf16(
    const u16* __restrict__ A, const u16* __restrict__ Bt,
    const float* __restrict__ bias, void* __restrict__ Cout,
    int M, int N, int K) {
  __shared__ __attribute__((aligned(16))) u16 As[128 * 64];
  __shared__ __attribute__((aligned(16))) u16 Bs[128 * 64];
  int tid = threadIdx.x;
  int m0 = blockIdx.y * 128;
  int n0 = blockIdx.x * 128;
  int w = tid >> 6, l = tid & 63;
  int wr = w >> 1, wc = w & 1;
  int lr = l & 15, lg = l >> 4;
  int rloc = l >> 3, cc = l & 7;
  int scc8 = (cc ^ rloc) * 8;  // source chunk XOR (elements)

  f32x4 acc[4][4];
#pragma unroll
  for (int i = 0; i < 4; i++)
#pragma unroll
    for (int j = 0; j < 4; j++) acc[i][j] = (f32x4)0.0f;

  for (int kt = 0; kt < K; kt += 64) {
    __syncthreads();
#pragma unroll
    for (int qq = 0; qq < 4; ++qq) {
      int row = 32 * w + 8 * qq + rloc;
      gl_lds16(A + (size_t)(m0 + row) * K + kt + scc8, &As[(32 * w + 8 * qq) * 64]);
      gl_lds16(Bt + (size_t)(n0 + row) * K + kt + scc8, &Bs[(32 * w + 8 * qq) * 64]);
    }
    __syncthreads();
#pragma unroll
    for (int kk = 0; kk < 2; ++kk) {
      bf16x8 af[4], bfr[4];
#pragma unroll
      for (int i = 0; i < 4; i++)
        af[i] = load_frag16(swz(As, wr * 64 + i * 16 + lr, kk * 64 + lg * 16));
#pragma unroll
      for (int j = 0; j < 4; j++)
        bfr[j] = load_frag16(swz(Bs, wc * 64 + j * 16 + lr, kk * 64 + lg * 16));
#pragma unroll
      for (int i = 0; i < 4; i++)
#pragma unroll
        for (int j = 0; j < 4; j++)
          acc[i][j] = __builtin_amdgcn_mfma_f32_16x16x32_bf16(af[i], bfr[j], acc[i][j], 0, 0, 0);
    }
  }
#pragma unroll
  for (int i = 0; i < 4; i++) {
#pragma unroll
    for (int j = 0; j < 4; j++) {
      int col = n0 + wc * 64 + j * 16 + lr;
      float bv = bias[col];
#pragma unroll
      for (int r = 0; r < 4; r++) {
        int row = m0 + wr * 64 + i * 16 + lg * 4 + r;
        float v = acc[i][j][r] + bv;
        if (OUT_BF16)
          ((u16*)Cout)[(size_t)row * N + col] = f32_to_bf16(v);
        else
          ((float*)Cout)[(size_t)row * N + col] = v;
      }
    }
  }
}

// ---------------- causal flash attention (v3) ----------------
// 128 threads (2 waves), each wave 32 q-rows; block = 64-row q-subtile.
// grid (16, 64); block x does subtile x then 31-x -> uniform 33 KV-iters.
// Swapped QK^T (St = K*Q^T) -> lane-local softmax; K/V double-buffered via
// global_load_lds; all LDS tiles [rows][64] with XOR swizzle.
__global__ __launch_bounds__(128, 2) void attn_kernel(
    const u16* __restrict__ qkvb, const u16* __restrict__ vTg,
    u16* __restrict__ attnb) {
  __shared__ __attribute__((aligned(16))) u16 Ks[2][64 * 64];
  __shared__ __attribute__((aligned(16))) u16 Vt[2][64 * 64];
  __shared__ __attribute__((aligned(16))) u16 Pl[2][32 * 64];
  int tid = threadIdx.x;
  int w = tid >> 6, l = tid & 63;
  int lr = l & 15, lg = l >> 4;
  int rloc = l >> 3, cc = l & 7;
  int scc8 = (cc ^ rloc) * 8;
  int bh = blockIdx.y;
  int b = bh >> 4, h = bh & 15;
  const u16* base = qkvb + (size_t)b * 2048 * 3072;
  const u16* kglob = base + 1024 + h * 64;
  const u16* vbase = vTg + (size_t)bh * 64 * 2048;
  u16* PlW = Pl[w];

#define STAGE_KV(bi, tt)                                                        \
  do {                                                                          \
    int kv0_ = (tt) * 64;                                                       \
    _Pragma("unroll")                                                           \
    for (int qq = 0; qq < 4; ++qq) {                                            \
      int row_ = 32 * w + 8 * qq + rloc;                                        \
      gl_lds16(kglob + (size_t)(kv0_ + row_) * 3072 + scc8,                     \
               &Ks[bi][(32 * w + 8 * qq) * 64]);                                \
      gl_lds16(vbase + (size_t)row_ * 2048 + kv0_ + scc8,                       \
               &Vt[bi][(32 * w + 8 * qq) * 64]);                                \
    }                                                                           \
  } while (0)

  for (int half = 0; half < 2; ++half) {
    int s = half ? 31 - (int)blockIdx.x : (int)blockIdx.x;
    int qb = s * 64;
    int nkv = s + 1;

    // Q fragments (scaled by 1/sqrt(64)=0.125, exact in bf16)
    bf16x8 qf[2][2];
#pragma unroll
    for (int i = 0; i < 2; i++)
#pragma unroll
      for (int kk = 0; kk < 2; kk++) {
        int row = qb + w * 32 + i * 16 + lr;
        uint4 v = *(const uint4*)(base + (size_t)row * 3072 + h * 64 + kk * 32 + lg * 8);
        u32 wd[4] = {v.x, v.y, v.z, v.w};
#pragma unroll
        for (int e = 0; e < 4; e++) {
          u16 lo = (u16)(wd[e] & 0xFFFFu), hi = (u16)(wd[e] >> 16);
          lo = (u16)(__builtin_bit_cast(u32, bf16_to_f32(lo) * 0.125f) >> 16);
          hi = (u16)(__builtin_bit_cast(u32, bf16_to_f32(hi) * 0.125f) >> 16);
          wd[e] = (u32)lo | ((u32)hi << 16);
        }
        uint4 sv; sv.x = wd[0]; sv.y = wd[1]; sv.z = wd[2]; sv.w = wd[3];
        qf[i][kk] = __builtin_bit_cast(bf16x8, sv);
      }

    float m_st[2] = {-1e30f, -1e30f};
    float l_st[2] = {0.f, 0.f};
    f32x4 of[2][4];
#pragma unroll
    for (int i = 0; i < 2; i++)
#pragma unroll
      for (int j = 0; j < 4; j++) of[i][j] = (f32x4)0.0f;

    STAGE_KV(0, 0);

    for (int t = 0; t < nkv; ++t) {
      int cur = t & 1;
      __syncthreads();  // staged data for t arrived; all waves done with buf cur
      if (t + 1 < nkv) STAGE_KV(cur ^ 1, t + 1);

      const u16* Kb = Ks[cur];
      const u16* Vb = Vt[cur];

      // St[j][i] = K_j * Q_i^T  (St[k][q]: col=lane&15 -> q, row -> k)
      f32x4 St[4][2];
#pragma unroll
      for (int j = 0; j < 4; j++)
#pragma unroll
        for (int i = 0; i < 2; i++) St[j][i] = (f32x4)0.0f;
#pragma unroll
      for (int kk = 0; kk < 2; ++kk) {
        bf16x8 kbf[4];
#pragma unroll
        for (int j = 0; j < 4; j++)
          kbf[j] = load_frag16(swz(Kb, j * 16 + lr, kk * 64 + lg * 16));
#pragma unroll
        for (int j = 0; j < 4; j++)
#pragma unroll
          for (int i = 0; i < 2; i++)
            St[j][i] = __builtin_amdgcn_mfma_f32_16x16x32_bf16(kbf[j], qf[i][kk], St[j][i], 0, 0, 0);
      }

      if (t == nkv - 1) {  // diagonal tile: mask k > q
#pragma unroll
        for (int j = 0; j < 4; j++)
#pragma unroll
          for (int i = 0; i < 2; i++)
#pragma unroll
            for (int r = 0; r < 4; r++) {
              int kabs = t * 64 + j * 16 + lg * 4 + r;
              int qabs = qb + w * 32 + i * 16 + lr;
              if (kabs > qabs) St[j][i][r] = -1e30f;
            }
      }

      // lane-local online softmax (each lane owns q = 16i+lr across 4 lg-slices)
#pragma unroll
      for (int i = 0; i < 2; ++i) {
        float tm = -1e30f;
#pragma unroll
        for (int j = 0; j < 4; j++)
#pragma unroll
          for (int r = 0; r < 4; r++) tm = fmaxf(tm, St[j][i][r]);
        tm = fmaxf(tm, __shfl_xor(tm, 16));
        tm = fmaxf(tm, __shfl_xor(tm, 32));
        float mn = fmaxf(m_st[i], tm);
        float fsc = __expf(m_st[i] - mn);
        m_st[i] = mn;
        float rs = 0.f;
#pragma unroll
        for (int j = 0; j < 4; ++j) {
          float p0 = __expf(St[j][i][0] - mn);
          float p1 = __expf(St[j][i][1] - mn);
          float p2 = __expf(St[j][i][2] - mn);
          float p3 = __expf(St[j][i][3] - mn);
          rs += (p0 + p1) + (p2 + p3);
          u32 w0 = (u32)f32_to_bf16(p0) | ((u32)f32_to_bf16(p1) << 16);
          u32 w1 = (u32)f32_to_bf16(p2) | ((u32)f32_to_bf16(p3) << 16);
          uint2 pk; pk.x = w0; pk.y = w1;
          *(uint2*)swzw(PlW, i * 16 + lr, j * 32 + lg * 8) = pk;  // elems 16j+4lg.. (+4)
        }
        rs += __shfl_xor(rs, 16);
        rs += __shfl_xor(rs, 32);
        l_st[i] = l_st[i] * fsc + rs;
        // rescale O (of-layout rows q = 16i + 4lg + r) with f from st-layout
#pragma unroll
        for (int r = 0; r < 4; ++r) {
          float ff = __shfl(fsc, lg * 4 + r);
#pragma unroll
          for (int jd = 0; jd < 4; jd++) of[i][jd][r] *= ff;
        }
      }

      // PV: O[q][d] += P[q][k] * V[k][d]  (A=P from Pl, B=V^T from Vt)
#pragma unroll
      for (int ks = 0; ks < 2; ++ks) {
        bf16x8 ap[2], vbf[4];
#pragma unroll
        for (int i = 0; i < 2; i++)
          ap[i] = load_frag16(swz(PlW, i * 16 + lr, ks * 64 + lg * 16));
#pragma unroll
        for (int jd = 0; jd < 4; jd++)
          vbf[jd] = load_frag16(swz(Vb, jd * 16 + lr, ks * 64 + lg * 16));
#pragma unroll
        for (int i = 0; i < 2; i++)
#pragma unroll
          for (int jd = 0; jd < 4; jd++)
            of[i][jd] = __builtin_amdgcn_mfma_f32_16x16x32_bf16(ap[i], vbf[jd], of[i][jd], 0, 0, 0);
      }
    }
    __syncthreads();  // protect staging buffers before next half / exit

    // epilogue: O /= lsum (bpermute lsum into of-layout), store bf16
#pragma unroll
    for (int i = 0; i < 2; i++) {
#pragma unroll
      for (int r = 0; r < 4; r++) {
        float ls = __shfl(l_st[i], lg * 4 + r);
        float inv = 1.0f / ls;
#pragma unroll
        for (int jd = 0; jd < 4; jd++) {
          int row = qb + w * 32 + i * 16 + lg * 4 + r;
          int col = h * 64 + jd * 16 + lr;
          attnb[((size_t)b * 2048 + row) * 1024 + col] = f32_to_bf16(of[i][jd][r] * inv);
        }
      }
    }
  }
#undef STAGE_KV
}

extern "C" void kernel_launch(void* const* d_in, const int* in_sizes, int n_in,
                              void* d_out, int out_size, void* d_ws, size_t ws_size,
                              hipStream_t stream) {
  const float* x = (const float*)d_in[0];
  const float* Wqkv = (const float*)d_in[1];
  const float* bqkv = (const float*)d_in[2];
  const float* Wproj = (const float*)d_in[3];
  const float* bproj = (const float*)d_in[4];
  float* out = (float*)d_out;

  char* ws = (char*)d_ws;
  u16* xb    = (u16*)(ws);                 // 8192*1024*2 (dead after gemm1)
  u16* vTg   = (u16*)(ws);                 // 64*64*2048*2 (reuses xb region)
  u16* wqT   = (u16*)(ws + 16777216);      // 3072*1024*2
  u16* wpT   = (u16*)(ws + 23068672);      // 1024*1024*2
  u16* qkvb  = (u16*)(ws + 25165824);      // 8192*3072*2
  u16* attnb = (u16*)(ws + 75497472);      // 8192*1024*2  (total ~92MB)

  cvt_f32_bf16<<<8192, 256, 0, stream>>>(x, xb, 8388608);
  transpose_cvt<<<dim3(96, 32), 256, 0, stream>>>(Wqkv, wqT, 1024, 3072);
  transpose_cvt<<<dim3(32, 32), 256, 0, stream>>>(Wproj, wpT, 1024, 1024);
  gemm_bf16<1><<<dim3(24, 64), 256, 0, stream>>>(xb, wqT, bqkv, (void*)qkvb, 8192, 3072, 1024);
  transpose_v<<<dim3(32, 64), 256, 0, stream>>>(qkvb, vTg);
  attn_kernel<<<dim3(16, 64), 128, 0, stream>>>(qkvb, vTg, attnb);
  gemm_bf16<0><<<dim3(8, 64), 256, 0, stream>>>(attnb, wpT, bproj, (void*)out, 8192, 1024, 1024);
}

// Round 4
// 174.355 us; speedup vs baseline: 2.0431x; 1.1264x over previous
//
#include <hip/hip_runtime.h>
#include <stdint.h>

#define DEV __device__ __forceinline__

typedef uint32_t u32;
typedef uint16_t u16;
typedef __attribute__((ext_vector_type(4))) float f32x4;
typedef __attribute__((ext_vector_type(8))) __bf16 bf16x8;

DEV u16 f32_to_bf16(float f) {
  u32 u = __builtin_bit_cast(u32, f);
  u += 0x7FFFu + ((u >> 16) & 1u);
  return (u16)(u >> 16);
}
DEV float bf16_to_f32(u16 h) {
  u32 u = ((u32)h) << 16;
  return __builtin_bit_cast(float, u);
}
DEV bf16x8 load_frag16(const u16* p) {
  return __builtin_bit_cast(bf16x8, *(const uint4*)p);
}
DEV float exp2_fast(float x) {
#if __has_builtin(__builtin_amdgcn_exp2f)
  return __builtin_amdgcn_exp2f(x);
#else
  float r;
  asm("v_exp_f32 %0, %1\n\ts_nop 0" : "=v"(r) : "v"(x));
  return r;
#endif
}
DEV u32 cvt_pk_bf16(float lo, float hi) {
  u32 r;
  asm("v_cvt_pk_bf16_f32 %0, %1, %2" : "=v"(r) : "v"(lo), "v"(hi));
  return r;
}

// global -> LDS direct (16B per lane, dest = wave-uniform base + lane*16)
DEV void gl_lds16(const u16* g, u16* l) {
  __builtin_amdgcn_global_load_lds(
      (__attribute__((address_space(1))) void*)(u16*)g,
      (__attribute__((address_space(3))) void*)l, 16, 0, 0);
}

// XOR-swizzled address into a [rows][64 bf16] tile (128 B rows).
DEV const u16* swz(const u16* basep, int row, int colByte) {
  return (const u16*)((const char*)basep + row * 128 + (colByte ^ ((row & 7) << 4)));
}
DEV u16* swzw(u16* basep, int row, int colByte) {
  return (u16*)((char*)basep + row * 128 + (colByte ^ ((row & 7) << 4)));
}

// ---------------- convert fp32 -> bf16 (elementwise) ----------------
__global__ void cvt_f32_bf16(const float* __restrict__ in, u16* __restrict__ out, int n) {
  int i = (blockIdx.x * 256 + threadIdx.x) * 4;
  if (i >= n) return;
  float4 v = *(const float4*)(in + i);
  ushort4 o;
  o.x = f32_to_bf16(v.x); o.y = f32_to_bf16(v.y);
  o.z = f32_to_bf16(v.z); o.w = f32_to_bf16(v.w);
  *(ushort4*)(out + i) = o;
}

// ------------- transpose + convert: in[R][C] f32 -> out[C][R] bf16 -------------
__global__ void transpose_cvt(const float* __restrict__ in, u16* __restrict__ out, int R, int C) {
  __shared__ float tile[32][33];
  int bx = blockIdx.x * 32;
  int by = blockIdx.y * 32;
  int tx = threadIdx.x & 31;
  int ty = threadIdx.x >> 5;
#pragma unroll
  for (int i = 0; i < 32; i += 8)
    tile[ty + i][tx] = in[(size_t)(by + ty + i) * C + bx + tx];
  __syncthreads();
#pragma unroll
  for (int i = 0; i < 32; i += 8)
    out[(size_t)(bx + ty + i) * R + by + tx] = f32_to_bf16(tile[tx][ty + i]);
}

// ------------- transpose V: qkvb[b*2048+l][3072] (V slice) -> vTg[bh][64][2048] -------------
__global__ void transpose_v(const u16* __restrict__ qkvb, u16* __restrict__ vTg) {
  const int LDT = 72;
  __shared__ __attribute__((aligned(16))) u16 t[64 * 72];
  int bh = blockIdx.y;
  int b = bh >> 4, h = bh & 15;
  int l0 = blockIdx.x * 64;
  int tid = threadIdx.x;
#pragma unroll
  for (int p = 0; p < 2; ++p) {
    int chunk = p * 256 + tid;
    int row = chunk >> 3, cc = chunk & 7;
    *(uint4*)(t + row * LDT + cc * 8) =
        *(const uint4*)(qkvb + (size_t)(b * 2048 + l0 + row) * 3072 + 2048 + h * 64 + cc * 8);
  }
  __syncthreads();
#pragma unroll
  for (int p = 0; p < 2; ++p) {
    int chunk = p * 256 + tid;
    int d = chunk >> 3, cc = chunk & 7;
    ushort4 o0, o1;
    o0.x = t[(cc * 8 + 0) * LDT + d]; o0.y = t[(cc * 8 + 1) * LDT + d];
    o0.z = t[(cc * 8 + 2) * LDT + d]; o0.w = t[(cc * 8 + 3) * LDT + d];
    o1.x = t[(cc * 8 + 4) * LDT + d]; o1.y = t[(cc * 8 + 5) * LDT + d];
    o1.z = t[(cc * 8 + 6) * LDT + d]; o1.w = t[(cc * 8 + 7) * LDT + d];
    u16* op = vTg + ((size_t)bh * 64 + d) * 2048 + l0;
    *(ushort4*)(op + cc * 8 + 0) = o0;
    *(ushort4*)(op + cc * 8 + 4) = o1;
  }
}

// ---------------- bf16 GEMM: C[M][N] = A[M][K] * Bt[N][K]^T + bias ----------------
template <int OUT_BF16>
__global__ __launch_bounds__(256, 2) void gemm_bf16(
    const u16* __restrict__ A, const u16* __restrict__ Bt,
    const float* __restrict__ bias, void* __restrict__ Cout,
    int M, int N, int K) {
  __shared__ __attribute__((aligned(16))) u16 As[128 * 64];
  __shared__ __attribute__((aligned(16))) u16 Bs[128 * 64];
  int tid = threadIdx.x;
  int m0 = blockIdx.y * 128;
  int n0 = blockIdx.x * 128;
  int w = tid >> 6, l = tid & 63;
  int wr = w >> 1, wc = w & 1;
  int lr = l & 15, lg = l >> 4;
  int rloc = l >> 3, cc = l & 7;
  int scc8 = (cc ^ rloc) * 8;

  f32x4 acc[4][4];
#pragma unroll
  for (int i = 0; i < 4; i++)
#pragma unroll
    for (int j = 0; j < 4; j++) acc[i][j] = (f32x4)0.0f;

  for (int kt = 0; kt < K; kt += 64) {
    __syncthreads();
#pragma unroll
    for (int qq = 0; qq < 4; ++qq) {
      int row = 32 * w + 8 * qq + rloc;
      gl_lds16(A + (size_t)(m0 + row) * K + kt + scc8, &As[(32 * w + 8 * qq) * 64]);
      gl_lds16(Bt + (size_t)(n0 + row) * K + kt + scc8, &Bs[(32 * w + 8 * qq) * 64]);
    }
    __syncthreads();
#pragma unroll
    for (int kk = 0; kk < 2; ++kk) {
      bf16x8 af[4], bfr[4];
#pragma unroll
      for (int i = 0; i < 4; i++)
        af[i] = load_frag16(swz(As, wr * 64 + i * 16 + lr, kk * 64 + lg * 16));
#pragma unroll
      for (int j = 0; j < 4; j++)
        bfr[j] = load_frag16(swz(Bs, wc * 64 + j * 16 + lr, kk * 64 + lg * 16));
#pragma unroll
      for (int i = 0; i < 4; i++)
#pragma unroll
        for (int j = 0; j < 4; j++)
          acc[i][j] = __builtin_amdgcn_mfma_f32_16x16x32_bf16(af[i], bfr[j], acc[i][j], 0, 0, 0);
    }
  }
#pragma unroll
  for (int i = 0; i < 4; i++) {
#pragma unroll
    for (int j = 0; j < 4; j++) {
      int col = n0 + wc * 64 + j * 16 + lr;
      float bv = bias[col];
#pragma unroll
      for (int r = 0; r < 4; r++) {
        int row = m0 + wr * 64 + i * 16 + lg * 4 + r;
        float v = acc[i][j][r] + bv;
        if (OUT_BF16)
          ((u16*)Cout)[(size_t)row * N + col] = f32_to_bf16(v);
        else
          ((float*)Cout)[(size_t)row * N + col] = v;
      }
    }
  }
}

// ---------------- causal flash attention (v4) ----------------
// 256 threads (4 waves), 128 q-rows per block (32/wave). grid (8, 64);
// block x does subtile x then 15-x -> uniform 34 KV-iters. Swapped QK^T,
// lane-local softmax in log2 domain, defer-max, cvt_pk packing, dbuf KV.
__global__ __launch_bounds__(256, 2) void attn_kernel(
    const u16* __restrict__ qkvb, const u16* __restrict__ vTg,
    u16* __restrict__ attnb) {
  __shared__ __attribute__((aligned(16))) u16 Ks[2][64 * 64];
  __shared__ __attribute__((aligned(16))) u16 Vt[2][64 * 64];
  __shared__ __attribute__((aligned(16))) u16 Pl[4][32 * 64];
  int tid = threadIdx.x;
  int w = tid >> 6, l = tid & 63;
  int lr = l & 15, lg = l >> 4;
  int rloc = l >> 3, cc = l & 7;
  int scc8 = (cc ^ rloc) * 8;
  int bh = blockIdx.y;
  int b = bh >> 4, h = bh & 15;
  const u16* base = qkvb + (size_t)b * 2048 * 3072;
  const u16* kglob = base + 1024 + h * 64;
  const u16* vbase = vTg + (size_t)bh * 64 * 2048;
  u16* PlW = Pl[w];
  // scale = 1/sqrt(64) * log2(e): softmax done with exp2 directly
  const float SCALE = 0.18033688011112042f;

#define STAGE_KV(bi, tt)                                                        \
  do {                                                                          \
    int kv0_ = (tt) * 64;                                                       \
    _Pragma("unroll")                                                           \
    for (int qq = 0; qq < 2; ++qq) {                                            \
      int row_ = 16 * w + 8 * qq + rloc;                                        \
      gl_lds16(kglob + (size_t)(kv0_ + row_) * 3072 + scc8,                     \
               &Ks[bi][(16 * w + 8 * qq) * 64]);                                \
      gl_lds16(vbase + (size_t)row_ * 2048 + kv0_ + scc8,                       \
               &Vt[bi][(16 * w + 8 * qq) * 64]);                                \
    }                                                                           \
  } while (0)

  for (int half = 0; half < 2; ++half) {
    int s = half ? 15 - (int)blockIdx.x : (int)blockIdx.x;
    int qb = s * 128;
    int nkv = 2 * s + 2;
    int tmax = 2 * s + (w >> 1);  // last (diagonal) tile for this wave

    // Q fragments, scaled by SCALE (RTNE via cvt_pk)
    bf16x8 qf[2][2];
#pragma unroll
    for (int i = 0; i < 2; i++)
#pragma unroll
      for (int kk = 0; kk < 2; kk++) {
        int row = qb + w * 32 + i * 16 + lr;
        uint4 v = *(const uint4*)(base + (size_t)row * 3072 + h * 64 + kk * 32 + lg * 8);
        u32 wd[4] = {v.x, v.y, v.z, v.w};
#pragma unroll
        for (int e = 0; e < 4; e++) {
          float flo = bf16_to_f32((u16)(wd[e] & 0xFFFFu)) * SCALE;
          float fhi = bf16_to_f32((u16)(wd[e] >> 16)) * SCALE;
          wd[e] = cvt_pk_bf16(flo, fhi);
        }
        uint4 sv; sv.x = wd[0]; sv.y = wd[1]; sv.z = wd[2]; sv.w = wd[3];
        qf[i][kk] = __builtin_bit_cast(bf16x8, sv);
      }

    float m_st[2] = {-1e30f, -1e30f};
    float l_st[2] = {0.f, 0.f};
    f32x4 of[2][4];
#pragma unroll
    for (int i = 0; i < 2; i++)
#pragma unroll
      for (int j = 0; j < 4; j++) of[i][j] = (f32x4)0.0f;

    STAGE_KV(0, 0);

    for (int t = 0; t < nkv; ++t) {
      int cur = t & 1;
      __syncthreads();  // staged data for t arrived; all waves done with buf cur
      if (t + 1 < nkv) STAGE_KV(cur ^ 1, t + 1);

      if (t <= tmax) {
        const u16* Kb = Ks[cur];
        const u16* Vb = Vt[cur];

        // St[j][i] = K_j * Q_i^T  (lane: q = 16i+lr, k = 16j+4lg+r)
        f32x4 St[4][2];
#pragma unroll
        for (int j = 0; j < 4; j++)
#pragma unroll
          for (int i = 0; i < 2; i++) St[j][i] = (f32x4)0.0f;
        __builtin_amdgcn_s_setprio(1);
#pragma unroll
        for (int kk = 0; kk < 2; ++kk) {
          bf16x8 kbf[4];
#pragma unroll
          for (int j = 0; j < 4; j++)
            kbf[j] = load_frag16(swz(Kb, j * 16 + lr, kk * 64 + lg * 16));
#pragma unroll
          for (int j = 0; j < 4; j++)
#pragma unroll
            for (int i = 0; i < 2; i++)
              St[j][i] = __builtin_amdgcn_mfma_f32_16x16x32_bf16(kbf[j], qf[i][kk], St[j][i], 0, 0, 0);
        }
        __builtin_amdgcn_s_setprio(0);

        if (t == tmax) {  // diagonal tile: mask k > q
#pragma unroll
          for (int j = 0; j < 4; j++)
#pragma unroll
            for (int i = 0; i < 2; i++)
#pragma unroll
              for (int r = 0; r < 4; r++) {
                int kabs = t * 64 + j * 16 + lg * 4 + r;
                int qabs = qb + w * 32 + i * 16 + lr;
                if (kabs > qabs) St[j][i][r] = -1e30f;
              }
        }

        // lane-local online softmax (log2 domain), defer-max THR=10
#pragma unroll
        for (int i = 0; i < 2; ++i) {
          float tm = -1e30f;
#pragma unroll
          for (int j = 0; j < 4; j++)
#pragma unroll
            for (int r = 0; r < 4; r++) tm = fmaxf(tm, St[j][i][r]);
          tm = fmaxf(tm, __shfl_xor(tm, 16));
          tm = fmaxf(tm, __shfl_xor(tm, 32));
          if (!__all((int)(tm <= m_st[i] + 10.0f))) {
            float mn = fmaxf(m_st[i], tm);
            float fsc = exp2_fast(m_st[i] - mn);
            m_st[i] = mn;
            l_st[i] *= fsc;
#pragma unroll
            for (int r = 0; r < 4; ++r) {
              float ff = __shfl(fsc, lg * 4 + r);
#pragma unroll
              for (int jd = 0; jd < 4; jd++) of[i][jd][r] *= ff;
            }
          }
          float rs = 0.f;
#pragma unroll
          for (int j = 0; j < 4; ++j) {
            float p0 = exp2_fast(St[j][i][0] - m_st[i]);
            float p1 = exp2_fast(St[j][i][1] - m_st[i]);
            float p2 = exp2_fast(St[j][i][2] - m_st[i]);
            float p3 = exp2_fast(St[j][i][3] - m_st[i]);
            rs += (p0 + p1) + (p2 + p3);
            uint2 pk;
            pk.x = cvt_pk_bf16(p0, p1);
            pk.y = cvt_pk_bf16(p2, p3);
            *(uint2*)swzw(PlW, i * 16 + lr, j * 32 + lg * 8) = pk;
          }
          rs += __shfl_xor(rs, 16);
          rs += __shfl_xor(rs, 32);
          l_st[i] += rs;
        }

        // PV: O[q][d] += P[q][k] * V[k][d]
        __builtin_amdgcn_s_setprio(1);
#pragma unroll
        for (int ks = 0; ks < 2; ++ks) {
          bf16x8 ap[2], vbf[4];
#pragma unroll
          for (int i = 0; i < 2; i++)
            ap[i] = load_frag16(swz(PlW, i * 16 + lr, ks * 64 + lg * 16));
#pragma unroll
          for (int jd = 0; jd < 4; jd++)
            vbf[jd] = load_frag16(swz(Vb, jd * 16 + lr, ks * 64 + lg * 16));
#pragma unroll
          for (int i = 0; i < 2; i++)
#pragma unroll
            for (int jd = 0; jd < 4; jd++)
              of[i][jd] = __builtin_amdgcn_mfma_f32_16x16x32_bf16(ap[i], vbf[jd], of[i][jd], 0, 0, 0);
        }
        __builtin_amdgcn_s_setprio(0);
      }
    }
    __syncthreads();  // protect staging buffers before next half / exit

    // epilogue: O /= lsum, store bf16 head-merged
#pragma unroll
    for (int i = 0; i < 2; i++) {
#pragma unroll
      for (int r = 0; r < 4; r++) {
        float ls = __shfl(l_st[i], lg * 4 + r);
        float inv = 1.0f / ls;
#pragma unroll
        for (int jd = 0; jd < 4; jd++) {
          int row = qb + w * 32 + i * 16 + lg * 4 + r;
          int col = h * 64 + jd * 16 + lr;
          attnb[((size_t)b * 2048 + row) * 1024 + col] = f32_to_bf16(of[i][jd][r] * inv);
        }
      }
    }
  }
#undef STAGE_KV
}

extern "C" void kernel_launch(void* const* d_in, const int* in_sizes, int n_in,
                              void* d_out, int out_size, void* d_ws, size_t ws_size,
                              hipStream_t stream) {
  const float* x = (const float*)d_in[0];
  const float* Wqkv = (const float*)d_in[1];
  const float* bqkv = (const float*)d_in[2];
  const float* Wproj = (const float*)d_in[3];
  const float* bproj = (const float*)d_in[4];
  float* out = (float*)d_out;

  char* ws = (char*)d_ws;
  u16* xb    = (u16*)(ws);                 // 8192*1024*2 (dead after gemm1)
  u16* vTg   = (u16*)(ws);                 // 64*64*2048*2 (reuses xb region)
  u16* wqT   = (u16*)(ws + 16777216);      // 3072*1024*2
  u16* wpT   = (u16*)(ws + 23068672);      // 1024*1024*2
  u16* qkvb  = (u16*)(ws + 25165824);      // 8192*3072*2
  u16* attnb = (u16*)(ws + 75497472);      // 8192*1024*2  (total ~92MB)

  cvt_f32_bf16<<<8192, 256, 0, stream>>>(x, xb, 8388608);
  transpose_cvt<<<dim3(96, 32), 256, 0, stream>>>(Wqkv, wqT, 1024, 3072);
  transpose_cvt<<<dim3(32, 32), 256, 0, stream>>>(Wproj, wpT, 1024, 1024);
  gemm_bf16<1><<<dim3(24, 64), 256, 0, stream>>>(xb, wqT, bqkv, (void*)qkvb, 8192, 3072, 1024);
  transpose_v<<<dim3(32, 64), 256, 0, stream>>>(qkvb, vTg);
  attn_kernel<<<dim3(8, 64), 256, 0, stream>>>(qkvb, vTg, attnb);
  gemm_bf16<0><<<dim3(8, 64), 256, 0, stream>>>(attnb, wpT, bproj, (void*)out, 8192, 1024, 1024);
}

// Round 5
// 165.128 us; speedup vs baseline: 2.1572x; 1.0559x over previous
//
#include <hip/hip_runtime.h>
#include <stdint.h>

#define DEV __device__ __forceinline__

typedef uint32_t u32;
typedef uint16_t u16;
typedef __attribute__((ext_vector_type(4))) float f32x4;
typedef __attribute__((ext_vector_type(8))) __bf16 bf16x8;

DEV u16 f32_to_bf16(float f) {
  u32 u = __builtin_bit_cast(u32, f);
  u += 0x7FFFu + ((u >> 16) & 1u);
  return (u16)(u >> 16);
}
DEV float bf16_to_f32(u16 h) {
  u32 u = ((u32)h) << 16;
  return __builtin_bit_cast(float, u);
}
DEV bf16x8 load_frag16(const u16* p) {
  return __builtin_bit_cast(bf16x8, *(const uint4*)p);
}
DEV float exp2_fast(float x) {
#if __has_builtin(__builtin_amdgcn_exp2f)
  return __builtin_amdgcn_exp2f(x);
#else
  float r;
  asm("v_exp_f32 %0, %1\n\ts_nop 0" : "=v"(r) : "v"(x));
  return r;
#endif
}
DEV u32 cvt_pk_bf16(float lo, float hi) {
  u32 r;
  asm("v_cvt_pk_bf16_f32 %0, %1, %2" : "=v"(r) : "v"(lo), "v"(hi));
  return r;
}

// global -> LDS direct (16B per lane, dest = wave-uniform base + lane*16)
DEV void gl_lds16(const u16* g, u16* l) {
  __builtin_amdgcn_global_load_lds(
      (__attribute__((address_space(1))) void*)(u16*)g,
      (__attribute__((address_space(3))) void*)l, 16, 0, 0);
}

// XOR-swizzled address into a [rows][64 bf16] tile (128 B rows).
DEV const u16* swz(const u16* basep, int row, int colByte) {
  return (const u16*)((const char*)basep + row * 128 + (colByte ^ ((row & 7) << 4)));
}
DEV u16* swzw(u16* basep, int row, int colByte) {
  return (u16*)((char*)basep + row * 128 + (colByte ^ ((row & 7) << 4)));
}

// ---------------- convert fp32 -> bf16 (elementwise) ----------------
__global__ void cvt_f32_bf16(const float* __restrict__ in, u16* __restrict__ out, int n) {
  int i = (blockIdx.x * 256 + threadIdx.x) * 4;
  if (i >= n) return;
  float4 v = *(const float4*)(in + i);
  ushort4 o;
  o.x = f32_to_bf16(v.x); o.y = f32_to_bf16(v.y);
  o.z = f32_to_bf16(v.z); o.w = f32_to_bf16(v.w);
  *(ushort4*)(out + i) = o;
}

// ------------- transpose + convert: in[R][C] f32 -> out[C][R] bf16 -------------
__global__ void transpose_cvt(const float* __restrict__ in, u16* __restrict__ out, int R, int C) {
  __shared__ float tile[32][33];
  int bx = blockIdx.x * 32;
  int by = blockIdx.y * 32;
  int tx = threadIdx.x & 31;
  int ty = threadIdx.x >> 5;
#pragma unroll
  for (int i = 0; i < 32; i += 8)
    tile[ty + i][tx] = in[(size_t)(by + ty + i) * C + bx + tx];
  __syncthreads();
#pragma unroll
  for (int i = 0; i < 32; i += 8)
    out[(size_t)(bx + ty + i) * R + by + tx] = f32_to_bf16(tile[tx][ty + i]);
}

// ------------- transpose V: qkvb[b*2048+l][3072] (V slice) -> vTg[bh][64][2048] -------------
__global__ void transpose_v(const u16* __restrict__ qkvb, u16* __restrict__ vTg) {
  const int LDT = 72;
  __shared__ __attribute__((aligned(16))) u16 t[64 * 72];
  int bh = blockIdx.y;
  int b = bh >> 4, h = bh & 15;
  int l0 = blockIdx.x * 64;
  int tid = threadIdx.x;
#pragma unroll
  for (int p = 0; p < 2; ++p) {
    int chunk = p * 256 + tid;
    int row = chunk >> 3, cc = chunk & 7;
    *(uint4*)(t + row * LDT + cc * 8) =
        *(const uint4*)(qkvb + (size_t)(b * 2048 + l0 + row) * 3072 + 2048 + h * 64 + cc * 8);
  }
  __syncthreads();
#pragma unroll
  for (int p = 0; p < 2; ++p) {
    int chunk = p * 256 + tid;
    int d = chunk >> 3, cc = chunk & 7;
    ushort4 o0, o1;
    o0.x = t[(cc * 8 + 0) * LDT + d]; o0.y = t[(cc * 8 + 1) * LDT + d];
    o0.z = t[(cc * 8 + 2) * LDT + d]; o0.w = t[(cc * 8 + 3) * LDT + d];
    o1.x = t[(cc * 8 + 4) * LDT + d]; o1.y = t[(cc * 8 + 5) * LDT + d];
    o1.z = t[(cc * 8 + 6) * LDT + d]; o1.w = t[(cc * 8 + 7) * LDT + d];
    u16* op = vTg + ((size_t)bh * 64 + d) * 2048 + l0;
    *(ushort4*)(op + cc * 8 + 0) = o0;
    *(ushort4*)(op + cc * 8 + 4) = o1;
  }
}

// ---------------- bf16 GEMM: C[M][N] = A[M][K] * Bt[N][K]^T + bias ----------------
// XCD-aware block swizzle (grid sizes here are multiples of 8).
template <int OUT_BF16>
__global__ __launch_bounds__(256, 2) void gemm_bf16(
    const u16* __restrict__ A, const u16* __restrict__ Bt,
    const float* __restrict__ bias, void* __restrict__ Cout,
    int M, int N, int K) {
  __shared__ __attribute__((aligned(16))) u16 As[128 * 64];
  __shared__ __attribute__((aligned(16))) u16 Bs[128 * 64];
  int tid = threadIdx.x;
  u32 nwg = gridDim.x * gridDim.y;
  u32 orig = blockIdx.y * gridDim.x + blockIdx.x;
  u32 wg = (orig & 7) * (nwg >> 3) + (orig >> 3);
  int m0 = (wg / gridDim.x) * 128;
  int n0 = (wg % gridDim.x) * 128;
  int w = tid >> 6, l = tid & 63;
  int wr = w >> 1, wc = w & 1;
  int lr = l & 15, lg = l >> 4;
  int rloc = l >> 3, cc = l & 7;
  int scc8 = (cc ^ rloc) * 8;

  f32x4 acc[4][4];
#pragma unroll
  for (int i = 0; i < 4; i++)
#pragma unroll
    for (int j = 0; j < 4; j++) acc[i][j] = (f32x4)0.0f;

  for (int kt = 0; kt < K; kt += 64) {
    __syncthreads();
#pragma unroll
    for (int qq = 0; qq < 4; ++qq) {
      int row = 32 * w + 8 * qq + rloc;
      gl_lds16(A + (size_t)(m0 + row) * K + kt + scc8, &As[(32 * w + 8 * qq) * 64]);
      gl_lds16(Bt + (size_t)(n0 + row) * K + kt + scc8, &Bs[(32 * w + 8 * qq) * 64]);
    }
    __syncthreads();
#pragma unroll
    for (int kk = 0; kk < 2; ++kk) {
      bf16x8 af[4], bfr[4];
#pragma unroll
      for (int i = 0; i < 4; i++)
        af[i] = load_frag16(swz(As, wr * 64 + i * 16 + lr, kk * 64 + lg * 16));
#pragma unroll
      for (int j = 0; j < 4; j++)
        bfr[j] = load_frag16(swz(Bs, wc * 64 + j * 16 + lr, kk * 64 + lg * 16));
#pragma unroll
      for (int i = 0; i < 4; i++)
#pragma unroll
        for (int j = 0; j < 4; j++)
          acc[i][j] = __builtin_amdgcn_mfma_f32_16x16x32_bf16(af[i], bfr[j], acc[i][j], 0, 0, 0);
    }
  }
#pragma unroll
  for (int i = 0; i < 4; i++) {
#pragma unroll
    for (int j = 0; j < 4; j++) {
      int col = n0 + wc * 64 + j * 16 + lr;
      float bv = bias[col];
#pragma unroll
      for (int r = 0; r < 4; r++) {
        int row = m0 + wr * 64 + i * 16 + lg * 4 + r;
        float v = acc[i][j][r] + bv;
        if (OUT_BF16)
          ((u16*)Cout)[(size_t)row * N + col] = f32_to_bf16(v);
        else
          ((float*)Cout)[(size_t)row * N + col] = v;
      }
    }
  }
}

// ---------------- causal flash attention (v5) ----------------
// 256 threads (4 waves), 128 q-rows per block. grid (8, 64), XCD-swizzled so
// all 8 q-blocks of one (b,h) share an XCD's L2. KV staged 128 rows per phase
// (two 64x64 swizzled sub-tiles) -> 17 uniform barrier phases per block.
__global__ __launch_bounds__(256, 2) void attn_kernel(
    const u16* __restrict__ qkvb, const u16* __restrict__ vTg,
    u16* __restrict__ attnb) {
  __shared__ __attribute__((aligned(16))) u16 Ks[2][2 * 64 * 64];
  __shared__ __attribute__((aligned(16))) u16 Vt[2][2 * 64 * 64];
  __shared__ __attribute__((aligned(16))) u16 Pl[4][32 * 64];
  int tid = threadIdx.x;
  int w = tid >> 6, l = tid & 63;
  int lr = l & 15, lg = l >> 4;
  int rloc = l >> 3, cc = l & 7;
  int scc8 = (cc ^ rloc) * 8;
  // XCD swizzle: nwg=512, cpx=64 -> 8 consecutive bh per XCD
  u32 orig = blockIdx.y * 8 + blockIdx.x;
  u32 wg = (orig & 7) * 64 + (orig >> 3);
  int bx = wg & 7;
  int bh = wg >> 3;
  int b = bh >> 4, h = bh & 15;
  const u16* base = qkvb + (size_t)b * 2048 * 3072;
  const u16* kglob = base + 1024 + h * 64;
  const u16* vbase = vTg + (size_t)bh * 64 * 2048;
  u16* PlW = Pl[w];
  int usub = w >> 1, wl = w & 1;  // staging role: sub-tile usub, half-band wl
  // scale = 1/sqrt(64) * log2(e): softmax done with exp2 directly
  const float SCALE = 0.18033688011112042f;

// stage 128 kv rows (two 64x64 sub-tiles for K and for V^T) into buffer bi
#define STAGE128(bi, tt)                                                        \
  do {                                                                          \
    int kv0_ = (tt) * 128;                                                      \
    _Pragma("unroll")                                                           \
    for (int qq = 0; qq < 4; ++qq) {                                            \
      int lrow_ = 32 * wl + 8 * qq;      /* local row block in sub-tile */      \
      gl_lds16(kglob + (size_t)(kv0_ + usub * 64 + lrow_ + rloc) * 3072 + scc8, \
               &Ks[bi][usub * 4096 + lrow_ * 64]);                              \
      gl_lds16(vbase + (size_t)(lrow_ + rloc) * 2048 + kv0_ + usub * 64 + scc8, \
               &Vt[bi][usub * 4096 + lrow_ * 64]);                              \
    }                                                                           \
  } while (0)

  for (int half = 0; half < 2; ++half) {
    int s = half ? 15 - bx : bx;
    int qb = s * 128;
    int nst = s + 1;               // 128-kv staged phases
    int tmax64 = 2 * s + (w >> 1); // last active 64-sub-tile for this wave

    // Q fragments, scaled by SCALE (RTNE via cvt_pk)
    bf16x8 qf[2][2];
#pragma unroll
    for (int i = 0; i < 2; i++)
#pragma unroll
      for (int kk = 0; kk < 2; kk++) {
        int row = qb + w * 32 + i * 16 + lr;
        uint4 v = *(const uint4*)(base + (size_t)row * 3072 + h * 64 + kk * 32 + lg * 8);
        u32 wd[4] = {v.x, v.y, v.z, v.w};
#pragma unroll
        for (int e = 0; e < 4; e++) {
          float flo = bf16_to_f32((u16)(wd[e] & 0xFFFFu)) * SCALE;
          float fhi = bf16_to_f32((u16)(wd[e] >> 16)) * SCALE;
          wd[e] = cvt_pk_bf16(flo, fhi);
        }
        uint4 sv; sv.x = wd[0]; sv.y = wd[1]; sv.z = wd[2]; sv.w = wd[3];
        qf[i][kk] = __builtin_bit_cast(bf16x8, sv);
      }

    float m_st[2] = {-1e30f, -1e30f};
    float l_st[2] = {0.f, 0.f};
    f32x4 of[2][4];
#pragma unroll
    for (int i = 0; i < 2; i++)
#pragma unroll
      for (int j = 0; j < 4; j++) of[i][j] = (f32x4)0.0f;

    STAGE128(0, 0);

    for (int t = 0; t < nst; ++t) {
      int cur = t & 1;
      __syncthreads();  // staged data for t arrived; all waves done with buf cur
      if (t + 1 < nst) STAGE128(cur ^ 1, t + 1);

#pragma unroll
      for (int u = 0; u < 2; ++u) {
        int t64 = 2 * t + u;
        if (t64 <= tmax64) {
          const u16* Kb = Ks[cur] + u * 4096;
          const u16* Vb = Vt[cur] + u * 4096;

          // St[j][i] = K_j * Q_i^T  (lane: q = 16i+lr, k = 16j+4lg+r)
          f32x4 St[4][2];
#pragma unroll
          for (int j = 0; j < 4; j++)
#pragma unroll
            for (int i = 0; i < 2; i++) St[j][i] = (f32x4)0.0f;
          __builtin_amdgcn_s_setprio(1);
#pragma unroll
          for (int kk = 0; kk < 2; ++kk) {
            bf16x8 kbf[4];
#pragma unroll
            for (int j = 0; j < 4; j++)
              kbf[j] = load_frag16(swz(Kb, j * 16 + lr, kk * 64 + lg * 16));
#pragma unroll
            for (int j = 0; j < 4; j++)
#pragma unroll
              for (int i = 0; i < 2; i++)
                St[j][i] = __builtin_amdgcn_mfma_f32_16x16x32_bf16(kbf[j], qf[i][kk], St[j][i], 0, 0, 0);
          }
          __builtin_amdgcn_s_setprio(0);

          if (t64 == tmax64) {  // diagonal tile: mask k > q
#pragma unroll
            for (int j = 0; j < 4; j++)
#pragma unroll
              for (int i = 0; i < 2; i++)
#pragma unroll
                for (int r = 0; r < 4; r++) {
                  int kabs = t64 * 64 + j * 16 + lg * 4 + r;
                  int qabs = qb + w * 32 + i * 16 + lr;
                  if (kabs > qabs) St[j][i][r] = -1e30f;
                }
          }

          // lane-local online softmax (log2 domain), defer-max THR=10
#pragma unroll
          for (int i = 0; i < 2; ++i) {
            float tm = -1e30f;
#pragma unroll
            for (int j = 0; j < 4; j++)
#pragma unroll
              for (int r = 0; r < 4; r++) tm = fmaxf(tm, St[j][i][r]);
            tm = fmaxf(tm, __shfl_xor(tm, 16));
            tm = fmaxf(tm, __shfl_xor(tm, 32));
            if (!__all((int)(tm <= m_st[i] + 10.0f))) {
              float mn = fmaxf(m_st[i], tm);
              float fsc = exp2_fast(m_st[i] - mn);
              m_st[i] = mn;
              l_st[i] *= fsc;
#pragma unroll
              for (int r = 0; r < 4; ++r) {
                float ff = __shfl(fsc, lg * 4 + r);
#pragma unroll
                for (int jd = 0; jd < 4; jd++) of[i][jd][r] *= ff;
              }
            }
            float rs = 0.f;
#pragma unroll
            for (int j = 0; j < 4; ++j) {
              float p0 = exp2_fast(St[j][i][0] - m_st[i]);
              float p1 = exp2_fast(St[j][i][1] - m_st[i]);
              float p2 = exp2_fast(St[j][i][2] - m_st[i]);
              float p3 = exp2_fast(St[j][i][3] - m_st[i]);
              rs += (p0 + p1) + (p2 + p3);
              uint2 pk;
              pk.x = cvt_pk_bf16(p0, p1);
              pk.y = cvt_pk_bf16(p2, p3);
              *(uint2*)swzw(PlW, i * 16 + lr, j * 32 + lg * 8) = pk;
            }
            rs += __shfl_xor(rs, 16);
            rs += __shfl_xor(rs, 32);
            l_st[i] += rs;
          }

          // PV: O[q][d] += P[q][k] * V[k][d]
          __builtin_amdgcn_s_setprio(1);
#pragma unroll
          for (int ks = 0; ks < 2; ++ks) {
            bf16x8 ap[2], vbf[4];
#pragma unroll
            for (int i = 0; i < 2; i++)
              ap[i] = load_frag16(swz(PlW, i * 16 + lr, ks * 64 + lg * 16));
#pragma unroll
            for (int jd = 0; jd < 4; jd++)
              vbf[jd] = load_frag16(swz(Vb, jd * 16 + lr, ks * 64 + lg * 16));
#pragma unroll
            for (int i = 0; i < 2; i++)
#pragma unroll
              for (int jd = 0; jd < 4; jd++)
                of[i][jd] = __builtin_amdgcn_mfma_f32_16x16x32_bf16(ap[i], vbf[jd], of[i][jd], 0, 0, 0);
          }
          __builtin_amdgcn_s_setprio(0);
        }
      }
    }
    __syncthreads();  // protect staging buffers before next half / exit

    // epilogue: O /= lsum, store bf16 head-merged
#pragma unroll
    for (int i = 0; i < 2; i++) {
#pragma unroll
      for (int r = 0; r < 4; r++) {
        float ls = __shfl(l_st[i], lg * 4 + r);
        float inv = 1.0f / ls;
#pragma unroll
        for (int jd = 0; jd < 4; jd++) {
          int row = qb + w * 32 + i * 16 + lg * 4 + r;
          int col = h * 64 + jd * 16 + lr;
          attnb[((size_t)b * 2048 + row) * 1024 + col] = f32_to_bf16(of[i][jd][r] * inv);
        }
      }
    }
  }
#undef STAGE128
}

extern "C" void kernel_launch(void* const* d_in, const int* in_sizes, int n_in,
                              void* d_out, int out_size, void* d_ws, size_t ws_size,
                              hipStream_t stream) {
  const float* x = (const float*)d_in[0];
  const float* Wqkv = (const float*)d_in[1];
  const float* bqkv = (const float*)d_in[2];
  const float* Wproj = (const float*)d_in[3];
  const float* bproj = (const float*)d_in[4];
  float* out = (float*)d_out;

  char* ws = (char*)d_ws;
  u16* xb    = (u16*)(ws);                 // 8192*1024*2 (dead after gemm1)
  u16* vTg   = (u16*)(ws);                 // 64*64*2048*2 (reuses xb region)
  u16* wqT   = (u16*)(ws + 16777216);      // 3072*1024*2
  u16* wpT   = (u16*)(ws + 23068672);      // 1024*1024*2
  u16* qkvb  = (u16*)(ws + 25165824);      // 8192*3072*2
  u16* attnb = (u16*)(ws + 75497472);      // 8192*1024*2  (total ~92MB)

  cvt_f32_bf16<<<8192, 256, 0, stream>>>(x, xb, 8388608);
  transpose_cvt<<<dim3(96, 32), 256, 0, stream>>>(Wqkv, wqT, 1024, 3072);
  transpose_cvt<<<dim3(32, 32), 256, 0, stream>>>(Wproj, wpT, 1024, 1024);
  gemm_bf16<1><<<dim3(24, 64), 256, 0, stream>>>(xb, wqT, bqkv, (void*)qkvb, 8192, 3072, 1024);
  transpose_v<<<dim3(32, 64), 256, 0, stream>>>(qkvb, vTg);
  attn_kernel<<<dim3(8, 64), 256, 0, stream>>>(qkvb, vTg, attnb);
  gemm_bf16<0><<<dim3(8, 64), 256, 0, stream>>>(attnb, wpT, bproj, (void*)out, 8192, 1024, 1024);
}